// Round 6
// baseline (87.347 us; speedup 1.0000x reference)
//
#include <hip/hip_runtime.h>

#define LSTRIDE 40
#define LPLANE  720        // 18 rows * 40 cols
#define MSTRIDE 35

__device__ __forceinline__ float fexp2(float x) { return __builtin_amdgcn_exp2f(x); }
__device__ __forceinline__ float flog2(float x) { return __builtin_amdgcn_logf(x); }

struct Node { float o0, o1, o2, s0, s1, s2; };

// L col k <-> global w = w0 - 4 + k ; row r <-> global h = h0 + r
__device__ __forceinline__ Node nd(const float* L, int r, int k) {
    const int i = r * LSTRIDE + k;
    Node n;
    n.o0 = L[i];              n.o1 = L[i + LPLANE];     n.o2 = L[i + 2 * LPLANE];
    n.s0 = L[i + 3 * LPLANE]; n.s1 = L[i + 4 * LPLANE]; n.s2 = L[i + 5 * LPLANE];
    return n;
}

// core symmetric-pair term: wsm*wr*sum(t^0.8) + wl*wsd*sum(t^2)
__device__ __forceinline__ float pair_core(const Node& I, const Node& J,
                                           float wsm, float wl, float wsd)
{
    float d0 = I.o0 - J.o0, d1 = I.o1 - J.o1, d2 = I.o2 - J.o2;
    float sO = fmaf(d0, d0, fmaf(d1, d1, d2 * d2));
    float t0 = fabsf(I.s0 - J.s0) + 1e-8f;
    float t1 = fabsf(I.s1 - J.s1) + 1e-8f;
    float t2 = fabsf(I.s2 - J.s2) + 1e-8f;
    float ps = fexp2(0.8f * flog2(t0)) + fexp2(0.8f * flog2(t1)) + fexp2(0.8f * flog2(t2));
    float wr = fexp2(-0.72134752044448169f * sO);   // exp(-0.5*sO)
    float sq = fmaf(t0, t0, fmaf(t1, t1, t2 * t2));
    return fmaf(wsm * wr, ps, wl * wsd * sq);
}

// interior pixel: all pair multiplicities are 1
__device__ __forceinline__ float pixel_fast(
    const Node& C, const Node& E, const Node& S, const Node& SE, const Node& SW,
    float mi, float mE, float mS, float mSE, float mSW)
{
    float a = fmaf(mi, 3e-16f - 1.1943215e-6f, 1.1943215e-6f);  // center offset
    a += pair_core(C, E,  2.f - mi - mE,  mi + mE,  0.60653065971263342f);
    a += pair_core(C, S,  2.f - mi - mS,  mi + mS,  0.60653065971263342f);
    a += pair_core(C, SE, 2.f - mi - mSE, mi + mSE, 0.36787944117144233f);
    a += pair_core(C, SW, 2.f - mi - mSW, mi + mSW, 0.36787944117144233f);
    return a;
}

// border pixel: reflection multiplicities / zero weights
__device__ __forceinline__ float pixel_border(
    const Node& C, const Node& E, const Node& S, const Node& SE, const Node& SW,
    float mi, float mE, float mS, float mSE, float mSW, int h, int w)
{
    float aE = (w == 0)   ? 2.f : 1.f, bE = (w == 510) ? 2.f : 1.f;
    float aS = (h == 0)   ? 2.f : 1.f, bS = (h == 510) ? 2.f : 1.f;
    float aW = (w == 511) ? 2.f : 1.f, bW = (w == 1)   ? 2.f : 1.f;
    bool  vE = (w <= 510), vS = (h <= 510);
    bool  vD = vS && vE,   vW = vS && (w >= 1);
    float cEf = vE ? aE : 0.f,      cEb = vE ? bE : 0.f;
    float cSf = vS ? aS : 0.f,      cSb = vS ? bS : 0.f;
    float cDf = vD ? aS * aE : 0.f, cDb = vD ? bS * bE : 0.f;
    float cWf = vW ? aS * aW : 0.f, cWb = vW ? bS * bW : 0.f;

    float a = fmaf(mi, 3e-16f - 1.1943215e-6f, 1.1943215e-6f);
    a += pair_core(C, E,  fmaf(cEf, -mi, cEf) + fmaf(cEb, -mE,  cEb), fmaf(cEf, mi, cEb * mE),  0.60653065971263342f);
    a += pair_core(C, S,  fmaf(cSf, -mi, cSf) + fmaf(cSb, -mS,  cSb), fmaf(cSf, mi, cSb * mS),  0.60653065971263342f);
    a += pair_core(C, SE, fmaf(cDf, -mi, cDf) + fmaf(cDb, -mSE, cDb), fmaf(cDf, mi, cDb * mSE), 0.36787944117144233f);
    a += pair_core(C, SW, fmaf(cWf, -mi, cWf) + fmaf(cWb, -mSW, cWb), fmaf(cWf, mi, cWb * mSW), 0.36787944117144233f);
    return a;
}

__global__ __launch_bounds__(256, 8) void smooth_loss_kernel(
    const float* __restrict__ orig, const float* __restrict__ smo,
    float* __restrict__ out)
{
    __shared__ float L[6 * LPLANE];     // 4320 floats = 17.3 KB
    __shared__ float M[17 * MSTRIDE];   // mask plane, cm <-> w0-1+cm
    __shared__ float wsum[4];

    const int bid  = blockIdx.x;        // 8 imgs * 32 trow * 16 tcol
    const int b    = bid >> 9;
    const int t    = bid & 511;
    const int trow = t >> 4;
    const int tcol = t & 15;
    const int h0 = trow << 4;           // 16-row tile
    const int w0 = tcol << 5;           // 32-col tile
    const int tid = threadIdx.x;
    const bool border = (tcol == 0) | (tcol == 15) | (trow == 0) | (trow == 31);

    // ---- staging: 1080 float4 jobs (6 planes x 18 rows x 10 chunks) ----
    for (int it = 0; it < 5; ++it) {
        const int j = it * 256 + tid;
        const int p   = j / 180;
        const int rem = j - p * 180;
        const int r   = rem / 10;
        const int q   = rem - r * 10;
        int gh = h0 + r; gh = gh > 511 ? 1022 - gh : gh;
        int wb = w0 - 4 + (q << 2);
        wb = wb < 0 ? 0 : (wb > 508 ? 508 : wb);   // clamped garbage only lands in zero-weight slots
        const float* base = (p < 3) ? orig : smo;
        const int ch = (p < 3) ? p : p - 3;
        const float* gp = base + ((b * 3 + ch) << 18) + (gh << 9) + wb;
        if (j < 1080)
            __builtin_amdgcn_global_load_lds(
                (const __attribute__((address_space(1))) unsigned int*)gp,
                (__attribute__((address_space(3))) unsigned int*)&L[(it * 256 + (tid & ~63)) * 4],
                16, 0, 0);
    }
    __syncthreads();

    // ---- pass 1: mask plane (17 rows x 34 cols) ----
    for (int e = tid; e < 578; e += 256) {
        const int r = e / 34, cm = e - r * 34;
        const int vb = r * LSTRIDE + cm + 3;
        float eo = 0.f, es = 0.f;
        #pragma unroll
        for (int p = 0; p < 3; ++p) {
            float c0 = L[p * LPLANE + vb];
            float d1 = c0 - L[p * LPLANE + vb + LSTRIDE];
            float d2 = c0 - L[p * LPLANE + vb + 1];
            eo += d1 * d1 + d2 * d2;
            float c1 = L[(p + 3) * LPLANE + vb];
            float f1 = c1 - L[(p + 3) * LPLANE + vb + LSTRIDE];
            float f2 = c1 - L[(p + 3) * LPLANE + vb + 1];
            es += f1 * f1 + f2 * f2;
        }
        M[r * MSTRIDE + cm] = (eo < 1.f && (es - eo) > 1.f) ? 1.f : 0.f;
    }
    __syncthreads();

    // ---- pass 2: horizontal pixel pair per thread ----
    const int qr = tid >> 4;            // 0..15 pixel row
    const int qc = tid & 15;            // 0..15 -> cols 2qc, 2qc+1
    const int c0 = qc << 1;

    // nodes: row qr cols c0..c0+2 ; row qr+1 cols c0-1..c0+2  (k = c+4)
    Node A0 = nd(L, qr,     c0 + 4), A1 = nd(L, qr,     c0 + 5), A2 = nd(L, qr, c0 + 6);
    Node B_1 = nd(L, qr + 1, c0 + 3), B0 = nd(L, qr + 1, c0 + 4);
    Node B1 = nd(L, qr + 1, c0 + 5), B2 = nd(L, qr + 1, c0 + 6);

    const int mb = qr * MSTRIDE + c0;   // M index of (row qr, col c0-1)
    float mA0 = M[mb + 1], mA1 = M[mb + 2], mA2 = M[mb + 3];
    float mB_1 = M[mb + MSTRIDE],     mB0 = M[mb + MSTRIDE + 1];
    float mB1  = M[mb + MSTRIDE + 2], mB2 = M[mb + MSTRIDE + 3];

    float acc;
    if (border) {
        acc  = pixel_border(A0, A1, B0, B1, B_1, mA0, mA1, mB0, mB1, mB_1,
                            h0 + qr, w0 + c0);
        acc += pixel_border(A1, A2, B1, B2, B0,  mA1, mA2, mB1, mB2, mB0,
                            h0 + qr, w0 + c0 + 1);
    } else {
        acc  = pixel_fast(A0, A1, B0, B1, B_1, mA0, mA1, mB0, mB1, mB_1);
        acc += pixel_fast(A1, A2, B1, B2, B0,  mA1, mA2, mB1, mB2, mB0);
    }

    acc *= (1.0f / 56623104.0f);        // mean over 8*9*3*512*512

    #pragma unroll
    for (int o = 32; o > 0; o >>= 1)
        acc += __shfl_down(acc, o, 64);

    const int lane = tid & 63;
    const int wid  = tid >> 6;
    if (lane == 0) wsum[wid] = acc;
    __syncthreads();
    if (tid == 0)
        atomicAdd(out, wsum[0] + wsum[1] + wsum[2] + wsum[3]);
}

extern "C" void kernel_launch(void* const* d_in, const int* in_sizes, int n_in,
                              void* d_out, int out_size, void* d_ws, size_t ws_size,
                              hipStream_t stream) {
    const float* orig = (const float*)d_in[0];
    const float* smo  = (const float*)d_in[1];
    float* out = (float*)d_out;

    (void)hipMemsetAsync(out, 0, sizeof(float), stream);
    smooth_loss_kernel<<<4096, 256, 0, stream>>>(orig, smo, out);
}

// Round 7
// 45.701 us; speedup vs baseline: 1.9113x; 1.9113x over previous
//
#include <hip/hip_runtime.h>

#define LSTRIDE 72
#define LPLANE  1224       // 17 rows * 72 cols
#define MSTRIDE 66

__device__ __forceinline__ float fexp2(float x) { return __builtin_amdgcn_exp2f(x); }
__device__ __forceinline__ float flog2(float x) { return __builtin_amdgcn_logf(x); }

struct Node { float o0, o1, o2, s0, s1, s2; };

// L col k <-> global w = w0 - 4 + k ; row r <-> global h = h0 + r
__device__ __forceinline__ Node nd(const float* L, int r, int k) {
    const int i = r * LSTRIDE + k;
    Node n;
    n.o0 = L[i];              n.o1 = L[i + LPLANE];     n.o2 = L[i + 2 * LPLANE];
    n.s0 = L[i + 3 * LPLANE]; n.s1 = L[i + 4 * LPLANE]; n.s2 = L[i + 5 * LPLANE];
    return n;
}

// core symmetric-pair term: wsm*wr*sum(t^0.8) + wl*wsd*sum(t^2)
__device__ __forceinline__ float pair_core(const Node& I, const Node& J,
                                           float wsm, float wl, float wsd)
{
    float d0 = I.o0 - J.o0, d1 = I.o1 - J.o1, d2 = I.o2 - J.o2;
    float sO = fmaf(d0, d0, fmaf(d1, d1, d2 * d2));
    float t0 = fabsf(I.s0 - J.s0) + 1e-8f;
    float t1 = fabsf(I.s1 - J.s1) + 1e-8f;
    float t2 = fabsf(I.s2 - J.s2) + 1e-8f;
    float ps = fexp2(0.8f * flog2(t0)) + fexp2(0.8f * flog2(t1)) + fexp2(0.8f * flog2(t2));
    float wr = fexp2(-0.72134752044448169f * sO);   // exp(-0.5*sO)
    float sq = fmaf(t0, t0, fmaf(t1, t1, t2 * t2));
    return fmaf(wsm * wr, ps, wl * wsd * sq);
}

// interior pixel: all pair multiplicities are 1
__device__ __forceinline__ float pixel_fast(
    const Node& C, const Node& E, const Node& S, const Node& SE, const Node& SW,
    float mi, float mE, float mS, float mSE, float mSW)
{
    float a = fmaf(mi, 3e-16f - 1.1943215e-6f, 1.1943215e-6f);  // center offset
    a += pair_core(C, E,  2.f - mi - mE,  mi + mE,  0.60653065971263342f);
    a += pair_core(C, S,  2.f - mi - mS,  mi + mS,  0.60653065971263342f);
    a += pair_core(C, SE, 2.f - mi - mSE, mi + mSE, 0.36787944117144233f);
    a += pair_core(C, SW, 2.f - mi - mSW, mi + mSW, 0.36787944117144233f);
    return a;
}

// border pixel: reflection multiplicities / zero weights
__device__ __forceinline__ float pixel_border(
    const Node& C, const Node& E, const Node& S, const Node& SE, const Node& SW,
    float mi, float mE, float mS, float mSE, float mSW, int h, int w)
{
    float aE = (w == 0)   ? 2.f : 1.f, bE = (w == 510) ? 2.f : 1.f;
    float aS = (h == 0)   ? 2.f : 1.f, bS = (h == 510) ? 2.f : 1.f;
    float aW = (w == 511) ? 2.f : 1.f, bW = (w == 1)   ? 2.f : 1.f;
    bool  vE = (w <= 510), vS = (h <= 510);
    bool  vD = vS && vE,   vW = vS && (w >= 1);
    float cEf = vE ? aE : 0.f,      cEb = vE ? bE : 0.f;
    float cSf = vS ? aS : 0.f,      cSb = vS ? bS : 0.f;
    float cDf = vD ? aS * aE : 0.f, cDb = vD ? bS * bE : 0.f;
    float cWf = vW ? aS * aW : 0.f, cWb = vW ? bS * bW : 0.f;

    float a = fmaf(mi, 3e-16f - 1.1943215e-6f, 1.1943215e-6f);
    a += pair_core(C, E,  fmaf(cEf, -mi, cEf) + fmaf(cEb, -mE,  cEb), fmaf(cEf, mi, cEb * mE),  0.60653065971263342f);
    a += pair_core(C, S,  fmaf(cSf, -mi, cSf) + fmaf(cSb, -mS,  cSb), fmaf(cSf, mi, cSb * mS),  0.60653065971263342f);
    a += pair_core(C, SE, fmaf(cDf, -mi, cDf) + fmaf(cDb, -mSE, cDb), fmaf(cDf, mi, cDb * mSE), 0.36787944117144233f);
    a += pair_core(C, SW, fmaf(cWf, -mi, cWf) + fmaf(cWb, -mSW, cWb), fmaf(cWf, mi, cWb * mSW), 0.36787944117144233f);
    return a;
}

__global__ __launch_bounds__(256, 4) void smooth_loss_kernel(
    const float* __restrict__ orig, const float* __restrict__ smo,
    float* __restrict__ out)
{
    __shared__ float L[6 * LPLANE];          // 7344 floats = 29.4 KB
    __shared__ unsigned char M[17 * MSTRIDE];// 1122 B; cm <-> col w0-1+cm
    __shared__ float wsum[4];

    const int bid  = blockIdx.x;        // 8 imgs * 32 trow * 8 tcol
    const int b    = bid >> 8;
    const int t    = bid & 255;
    const int trow = t >> 3;
    const int tcol = t & 7;
    const int h0 = trow << 4;           // 16-row tile
    const int w0 = tcol << 6;           // 64-col tile
    const int tid = threadIdx.x;
    const bool border = (tcol == 0) | (tcol == 7) | (trow == 0) | (trow == 31);

    // ---- staging: 1836 float4 jobs (6 planes x 17 rows x 18 chunks) ----
    for (int it = 0; it < 8; ++it) {
        const int j = it * 256 + tid;
        const int p   = j / 306;
        const int rem = j - p * 306;
        const int r   = rem / 18;
        const int q   = rem - r * 18;
        int gh = h0 + r; gh = gh > 511 ? 1022 - gh : gh;
        int wb = w0 - 4 + (q << 2);
        wb = wb < 0 ? 0 : (wb > 508 ? 508 : wb);   // clamped garbage lands only in zero-weight slots
        const float* base = (p < 3) ? orig : smo;
        const int ch = (p < 3) ? p : p - 3;
        const float* gp = base + ((b * 3 + ch) << 18) + (gh << 9) + wb;
        if (j < 1836)
            __builtin_amdgcn_global_load_lds(
                (const __attribute__((address_space(1))) unsigned int*)gp,
                (__attribute__((address_space(3))) unsigned int*)&L[(it * 256 + (tid & ~63)) * 4],
                16, 0, 0);
    }
    __syncthreads();

    // ---- fix-up (tcol==7 only): k=68 <-> w=512 -> reflect 510, feeds the live mask at col 511 ----
    if (tcol == 7) {
        for (int j2 = tid; j2 < 102; j2 += 256) {
            const int p = j2 / 17, r = j2 - p * 17;
            int gh = h0 + r; gh = gh > 511 ? 1022 - gh : gh;
            const float* base = (p < 3) ? orig : smo;
            const int ch = (p < 3) ? p : p - 3;
            L[p * LPLANE + r * LSTRIDE + 68] = base[((b * 3 + ch) << 18) + (gh << 9) + 510];
        }
        __syncthreads();
    }

    // ---- pass 1: mask plane (17 rows x 66 cols), uchar ----
    for (int e = tid; e < 1122; e += 256) {
        const int r = e / 66, cm = e - r * 66;
        const int vb = r * LSTRIDE + cm + 3;
        float eo = 0.f, es = 0.f;
        #pragma unroll
        for (int p = 0; p < 3; ++p) {
            float c0 = L[p * LPLANE + vb];
            float d1 = c0 - L[p * LPLANE + vb + LSTRIDE];
            float d2 = c0 - L[p * LPLANE + vb + 1];
            eo += d1 * d1 + d2 * d2;
            float c1 = L[(p + 3) * LPLANE + vb];
            float f1 = c1 - L[(p + 3) * LPLANE + vb + LSTRIDE];
            float f2 = c1 - L[(p + 3) * LPLANE + vb + 1];
            es += f1 * f1 + f2 * f2;
        }
        M[r * MSTRIDE + cm] = (eo < 1.f && (es - eo) > 1.f) ? 1 : 0;
    }
    __syncthreads();

    // ---- pass 2: 2x2 pixel quad per thread ----
    const int qr = tid >> 5;            // 0..7  -> pixel rows 2qr, 2qr+1
    const int qc = tid & 31;            // 0..31 -> pixel cols 2qc, 2qc+1
    const int r0 = qr << 1;
    const int c0 = qc << 1;
    const int kb = c0 + 3;              // k of col c0-1

    float acc = 0.f;
    {
        // phase A: node rows r0 (3 cols), r0+1 (4 cols)
        Node A1 = nd(L, r0,     kb + 1), A2 = nd(L, r0, kb + 2), A3 = nd(L, r0, kb + 3);
        Node B0 = nd(L, r0 + 1, kb),     B1 = nd(L, r0 + 1, kb + 1);
        Node B2 = nd(L, r0 + 1, kb + 2), B3 = nd(L, r0 + 1, kb + 3);

        const int mb = r0 * MSTRIDE + c0;     // M index of (row r0, col c0-1)
        float mA1 = (float)M[mb + 1], mA2 = (float)M[mb + 2], mA3 = (float)M[mb + 3];
        float mB0 = (float)M[mb + MSTRIDE],     mB1 = (float)M[mb + MSTRIDE + 1];
        float mB2 = (float)M[mb + MSTRIDE + 2], mB3 = (float)M[mb + MSTRIDE + 3];

        if (border) {
            acc += pixel_border(A1, A2, B1, B2, B0, mA1, mA2, mB1, mB2, mB0,
                                h0 + r0, w0 + c0);
            acc += pixel_border(A2, A3, B2, B3, B1, mA2, mA3, mB2, mB3, mB1,
                                h0 + r0, w0 + c0 + 1);
        } else {
            acc += pixel_fast(A1, A2, B1, B2, B0, mA1, mA2, mB1, mB2, mB0);
            acc += pixel_fast(A2, A3, B2, B3, B1, mA2, mA3, mB2, mB3, mB1);
        }

        // phase B: node row r0+2
        Node C0 = nd(L, r0 + 2, kb),     C1 = nd(L, r0 + 2, kb + 1);
        Node C2 = nd(L, r0 + 2, kb + 2), C3 = nd(L, r0 + 2, kb + 3);
        float mC0 = (float)M[mb + 2 * MSTRIDE],     mC1 = (float)M[mb + 2 * MSTRIDE + 1];
        float mC2 = (float)M[mb + 2 * MSTRIDE + 2], mC3 = (float)M[mb + 2 * MSTRIDE + 3];

        if (border) {
            acc += pixel_border(B1, B2, C1, C2, C0, mB1, mB2, mC1, mC2, mC0,
                                h0 + r0 + 1, w0 + c0);
            acc += pixel_border(B2, B3, C2, C3, C1, mB2, mB3, mC2, mC3, mC1,
                                h0 + r0 + 1, w0 + c0 + 1);
        } else {
            acc += pixel_fast(B1, B2, C1, C2, C0, mB1, mB2, mC1, mC2, mC0);
            acc += pixel_fast(B2, B3, C2, C3, C1, mB2, mB3, mC2, mC3, mC1);
        }
    }

    acc *= (1.0f / 56623104.0f);        // mean over 8*9*3*512*512

    #pragma unroll
    for (int o = 32; o > 0; o >>= 1)
        acc += __shfl_down(acc, o, 64);

    const int lane = tid & 63;
    const int wid  = tid >> 6;
    if (lane == 0) wsum[wid] = acc;
    __syncthreads();
    if (tid == 0)
        atomicAdd(out, wsum[0] + wsum[1] + wsum[2] + wsum[3]);
}

extern "C" void kernel_launch(void* const* d_in, const int* in_sizes, int n_in,
                              void* d_out, int out_size, void* d_ws, size_t ws_size,
                              hipStream_t stream) {
    const float* orig = (const float*)d_in[0];
    const float* smo  = (const float*)d_in[1];
    float* out = (float*)d_out;

    (void)hipMemsetAsync(out, 0, sizeof(float), stream);
    smooth_loss_kernel<<<2048, 256, 0, stream>>>(orig, smo, out);
}